// Round 18
// baseline (45.314 us; speedup 1.0000x reference)
//
#include <hip/hip_runtime.h>
#include <float.h>

#define MM 256
#define PP 2097152            // fixed pair-list length
#define NBLK 512              // 512 slots: 128 structures x 4 row-blocks
#define CBLK 256              // count grid: 128 structures x 2 half-blocks
#define GTH (NBLK * 256)
#define CAP 1024              // staged pairs per pack batch
#define SLOTCAP 16384         // hard per-slot max (64 rows x 256 cols)
// Largest fp32 sq with rn(sqrt(sq)) < 5.0f  (== 25 - 2*ulp(25); boundary-exact)
#define SQMAX 24.999996185302734375f

typedef unsigned long long u64;

// ws layout (floats): wsD[512*SLOTCAP] | wsI[512*2*SLOTCAP] | wsF[512*3*SLOTCAP]
//                     | bsums int[NBLK] | minvec float[3]   (~201.5 MB total)

__device__ inline void wave_min3(float& x, float& y, float& z) {
    #pragma unroll
    for (int off = 32; off > 0; off >>= 1) {
        x = fminf(x, __shfl_xor(x, off, 64));
        y = fminf(y, __shfl_xor(y, off, 64));
        z = fminf(z, __shfl_xor(z, off, 64));
    }
}

// ---------------------------------------------------------------------------
// Geometry: slot b2 = b*4+rblk covers rows rblk*64..+64 of structure b;
// slot-thread tt = i_loc*4+c handles (row i_loc, j-chunk c); global slot
// b2*256+tt is lexicographic in (b,i,j). fp32 replicates the reference
// exactly: pos=coord-min (rn sub), diff=pos_j-pos_i, sq=((dx*dx+dy*dy)+dz*dz)
// no-FMA; membership sq<=SQMAX (== rn(sqrt(sq))<5 exactly); d=rn(sqrt) for
// hits only. fmin exact & order-independent -> matches jnp.min bitwise.
// ---------------------------------------------------------------------------

// K1 (256 blocks x 512 thr): redundant global min (100 MB L2), count, and
// PACK: per-slot pairs staged via LDS planes, flushed to slot-local ALIGNED
// bases in ws (no global scan needed -> no masks array, no recompute later).
__global__ void __launch_bounds__(512)
count_k(const float* __restrict__ coord, float* __restrict__ minvec,
        float* __restrict__ wsD, float* __restrict__ wsI,
        float* __restrict__ wsF, int* __restrict__ bsums) {
    const int cb = blockIdx.x;           // structure b = cb>>1, half h = cb&1
    const int b = cb >> 1, h = cb & 1;
    const int t = threadIdx.x;           // 0..511
    const int lane = t & 63, w = t >> 6; // w 0..7

    __shared__ float4 tile4[4][65];
    __shared__ float lmin[3][8];
    __shared__ int wsumS[2][4];          // per-slot wave sums
    __shared__ __align__(16) float sd[CAP];
    __shared__ __align__(16) float sind[2 * CAP];
    __shared__ __align__(16) float sdf[3 * CAP];

    // redundant global min: 24576 float4 = 8192 triplets (4 atoms each)
    const float4* c4 = reinterpret_cast<const float4*>(coord);
    float mx = FLT_MAX, my = FLT_MAX, mz = FLT_MAX;
    #pragma unroll 4
    for (int k = 0; k < 16; ++k) {
        const int basei = (k * 512 + t) * 3;
        const float4 f0 = c4[basei + 0];
        const float4 f1 = c4[basei + 1];
        const float4 f2 = c4[basei + 2];
        mx = fminf(mx, fminf(fminf(f0.x, f0.w), fminf(f1.z, f2.y)));
        my = fminf(my, fminf(fminf(f0.y, f1.x), fminf(f1.w, f2.z)));
        mz = fminf(mz, fminf(fminf(f0.z, f1.y), fminf(f2.x, f2.w)));
    }
    wave_min3(mx, my, mz);
    if (lane == 0) { lmin[0][w] = mx; lmin[1][w] = my; lmin[2][w] = mz; }
    __syncthreads();
    mx = fminf(fminf(fminf(lmin[0][0], lmin[0][1]), fminf(lmin[0][2], lmin[0][3])),
               fminf(fminf(lmin[0][4], lmin[0][5]), fminf(lmin[0][6], lmin[0][7])));
    my = fminf(fminf(fminf(lmin[1][0], lmin[1][1]), fminf(lmin[1][2], lmin[1][3])),
               fminf(fminf(lmin[1][4], lmin[1][5]), fminf(lmin[1][6], lmin[1][7])));
    mz = fminf(fminf(fminf(lmin[2][0], lmin[2][1]), fminf(lmin[2][2], lmin[2][3])),
               fminf(fminf(lmin[2][4], lmin[2][5]), fminf(lmin[2][6], lmin[2][7])));
    if (cb == 0 && t == 0) { minvec[0] = mx; minvec[1] = my; minvec[2] = mz; }

    // stage the whole structure's tile (shifted); threads 0..255
    if (t < 256) {
        const int ja = b * MM + t;
        tile4[t >> 6][t & 63] = make_float4(__fsub_rn(coord[3 * ja + 0], mx),
                                            __fsub_rn(coord[3 * ja + 1], my),
                                            __fsub_rn(coord[3 * ja + 2], mz), 0.0f);
    }
    __syncthreads();

    // count: hit bitmask; slot sIdx = t>>8 (0/1), b2 = b*4 + 2h + sIdx
    const int sIdx = t >> 8;
    const int rblk = 2 * h + sIdx;
    const int tt = t & 255;
    const int i_loc = tt >> 2, c = tt & 3;
    const float4 pi4 = tile4[rblk][i_loc];
    u64 mask = 0ULL;
    for (int jj = 0; jj < 64; ++jj) {
        float4 v = tile4[c][jj];
        float dx = __fsub_rn(v.x, pi4.x);
        float dy = __fsub_rn(v.y, pi4.y);
        float dz = __fsub_rn(v.z, pi4.z);
        float sq = __fadd_rn(__fadd_rn(__fmul_rn(dx, dx), __fmul_rn(dy, dy)),
                             __fmul_rn(dz, dz));
        if (sq > 0.0f && sq <= SQMAX) mask |= (1ULL << jj);
    }
    const int cnt = __popcll(mask);
    int incl = cnt;
    #pragma unroll
    for (int off = 1; off < 64; off <<= 1) {
        int v = __shfl_up(incl, off, 64);
        if (lane >= off) incl += v;
    }
    if (lane == 63) wsumS[sIdx][w & 3] = incl;
    __syncthreads();
    const int agg0 = wsumS[0][0] + wsumS[0][1] + wsumS[0][2] + wsumS[0][3];
    const int agg1 = wsumS[1][0] + wsumS[1][1] + wsumS[1][2] + wsumS[1][3];
    int woff = 0;
    for (int k = 0; k < (w & 3); ++k) woff += wsumS[sIdx][k];
    const int lexcl = woff + incl - cnt;     // slot-local exclusive prefix
    if (t == 0) {
        bsums[b * 4 + 2 * h + 0] = agg0;
        bsums[b * 4 + 2 * h + 1] = agg1;
    }
    __syncthreads();

    // pack each slot into ws at slot-local aligned bases (batched via LDS)
    const int gi = b * MM + rblk * 64 + i_loc;
    const int gj0 = b * MM + c * 64;
    for (int s = 0; s < 2; ++s) {
        const int aggS = s ? agg1 : agg0;
        const int b2 = b * 4 + 2 * h + s;
        const int nbat = (aggS + CAP - 1) / CAP;
        for (int bb = 0; bb < nbat; ++bb) {
            const int wlo = bb * CAP, whi = wlo + CAP;
            if (sIdx == s) {                 // this half scatters its hits
                int q = lexcl;
                u64 mm = mask;
                while (mm) {
                    const int jj = __ffsll((long long)mm) - 1;
                    mm &= mm - 1;
                    if (q >= whi) break;
                    if (q >= wlo) {
                        float4 v = tile4[c][jj];
                        float dx = __fsub_rn(v.x, pi4.x);
                        float dy = __fsub_rn(v.y, pi4.y);
                        float dz = __fsub_rn(v.z, pi4.z);
                        float sq = __fadd_rn(__fadd_rn(__fmul_rn(dx, dx),
                                                       __fmul_rn(dy, dy)),
                                             __fmul_rn(dz, dz));
                        const int sl = q - wlo;
                        sd[sl] = __fsqrt_rn(sq);
                        sind[2 * sl + 0] = (float)gi;
                        sind[2 * sl + 1] = (float)(gj0 + jj);
                        sdf[3 * sl + 0] = dx;
                        sdf[3 * sl + 1] = dy;
                        sdf[3 * sl + 2] = dz;
                    }
                    q++;
                }
            }
            __syncthreads();
            const int nq = ((aggS - wlo) < CAP) ? (aggS - wlo) : CAP;
            // flush (all 512 threads) to aligned ws bases
            {
                float* dst = wsD + (size_t)b2 * SLOTCAP + wlo;
                const int nb4 = nq >> 2;
                for (int m = t; m < nb4; m += 512)
                    reinterpret_cast<float4*>(dst)[m] =
                        reinterpret_cast<const float4*>(sd)[m];
                for (int e = (nb4 << 2) + t; e < nq; e += 512) dst[e] = sd[e];
            }
            {
                float* dst = wsI + (size_t)b2 * 2 * SLOTCAP + 2 * wlo;
                const int n2 = 2 * nq, nb4 = n2 >> 2;
                for (int m = t; m < nb4; m += 512)
                    reinterpret_cast<float4*>(dst)[m] =
                        reinterpret_cast<const float4*>(sind)[m];
                for (int e = (nb4 << 2) + t; e < n2; e += 512) dst[e] = sind[e];
            }
            {
                float* dst = wsF + (size_t)b2 * 3 * SLOTCAP + 3 * wlo;
                const int n3 = 3 * nq, nb4 = n3 >> 2;
                for (int m = t; m < nb4; m += 512)
                    reinterpret_cast<float4*>(dst)[m] =
                        reinterpret_cast<const float4*>(sdf)[m];
                for (int e = (nb4 << 2) + t; e < n3; e += 512) dst[e] = sdf[e];
            }
            __syncthreads();
        }
    }
}

// Copy n elements src(global, aligned base) -> dst(global) with dest-aligned
// float4 stores; scalar loads; scalar edges.
__device__ inline void copy_plane(const float* __restrict__ src, int n,
                                  float* __restrict__ dstBase, int t) {
    if (n <= 0) return;
    // dstBase points at element 0 of dest range; align stores on dest quads.
    const uintptr_t addr = (uintptr_t)dstBase;
    const int shift = (int)((addr >> 2) & 3);  // dest elem 0 is at quad offset
    // quad q (dest-aligned) covers dest elems [4q - shift, 4q - shift + 4)
    const int nq = (n + shift + 3) >> 2;
    float* dstQ = dstBase - shift;             // 16B-aligned
    for (int m = t; m < nq; m += 256) {
        const int e0 = 4 * m - shift;          // first dest elem of this quad
        if (e0 >= 0 && e0 + 4 <= n) {
            float4 v;
            v.x = src[e0 + 0]; v.y = src[e0 + 1];
            v.z = src[e0 + 2]; v.w = src[e0 + 3];
            reinterpret_cast<float4*>(dstQ)[m] = v;
        } else {
            const int a = e0 < 0 ? 0 : e0;
            const int bmax = (e0 + 4 < n) ? (e0 + 4) : n;
            for (int e = a; e < bmax; ++e) dstBase[e] = src[e];
        }
    }
}

// K2 (512 blocks x 256 thr): wave-0 scan of bsums -> base/total; pure
// streaming copy of the slot's 3 packed planes to the compacted output
// positions; grid-stride tail zero. Output: ind2 [0,2P) {gi,gj}, d [2P,3P),
// df [3P,6P).
__global__ void __launch_bounds__(256)
write_k(const float* __restrict__ wsD, const float* __restrict__ wsI,
        const float* __restrict__ wsF, const int* __restrict__ bsums,
        float* __restrict__ outF) {
    const int b2 = blockIdx.x;
    const int t = threadIdx.x;
    const int lane = t & 63, w = t >> 6;

    __shared__ int pre[NBLK];
    __shared__ int sTot;

    if (w == 0) {
        int v[8]; int s = 0;
        #pragma unroll
        for (int q = 0; q < 8; ++q) { v[q] = bsums[lane * 8 + q]; s += v[q]; }
        int isum = s;
        #pragma unroll
        for (int off = 1; off < 64; off <<= 1) {
            int u = __shfl_up(isum, off, 64);
            if (lane >= off) isum += u;
        }
        int run = isum - s;                       // exclusive prefix, lane-major
        #pragma unroll
        for (int q = 0; q < 8; ++q) { pre[lane * 8 + q] = run; run += v[q]; }
        if (lane == 63) sTot = run;
    }
    __syncthreads();
    const int base = pre[b2];
    const int aggFull = bsums[b2];
    const int total = (sTot < PP) ? sTot : PP;

    // clamp agg so writes stay within [0, PP)
    int agg = aggFull;
    if (base >= PP) agg = 0;
    else if (base + agg > PP) agg = PP - base;

    copy_plane(wsD + (size_t)b2 * SLOTCAP,     agg,     outF + 2 * PP + base,     t);
    copy_plane(wsI + (size_t)b2 * 2 * SLOTCAP, 2 * agg, outF + 2 * base,          t);
    copy_plane(wsF + (size_t)b2 * 3 * SLOTCAP, 3 * agg, outF + 3 * PP + 3 * base, t);

    // tail zeroing (disjoint from pair region; coalesced float4)
    const int g = b2 * 256 + t;
    const float4 z4 = make_float4(0.f, 0.f, 0.f, 0.f);
    float4* o4 = reinterpret_cast<float4*>(outF);
    {   // region 1: [2*total, 2*PP)
        const int lo = 2 * total, hi = 2 * PP;
        int a = (lo + 3) & ~3; if (a > hi) a = hi;
        if (g < a - lo) outF[lo + g] = 0.0f;
        for (int q = (a >> 2) + g; q < (hi >> 2); q += GTH) o4[q] = z4;
    }
    {   // region 2: [2*PP + total, 3*PP)
        const int lo = 2 * PP + total, hi = 3 * PP;
        int a = (lo + 3) & ~3; if (a > hi) a = hi;
        if (g < a - lo) outF[lo + g] = 0.0f;
        for (int q = (a >> 2) + g; q < (hi >> 2); q += GTH) o4[q] = z4;
    }
    {   // region 3: [3*PP + 3*total, 6*PP)
        const int lo = 3 * PP + 3 * total, hi = 6 * PP;
        int a = (lo + 3) & ~3; if (a > hi) a = hi;
        if (g < a - lo) outF[lo + g] = 0.0f;
        for (int q = (a >> 2) + g; q < (hi >> 2); q += GTH) o4[q] = z4;
    }
}

extern "C" void kernel_launch(void* const* d_in, const int* in_sizes, int n_in,
                              void* d_out, int out_size, void* d_ws, size_t ws_size,
                              hipStream_t stream) {
    const float* coord = (const float*)d_in[0];
    // d_in[1] (ind_1) structurally encoded (B contiguous blocks of M); unused.
    float* outF = (float*)d_out;

    float* wsD    = (float*)d_ws;                          // 512*SLOTCAP
    float* wsI    = wsD + (size_t)NBLK * SLOTCAP;          // 512*2*SLOTCAP
    float* wsF    = wsI + (size_t)NBLK * 2 * SLOTCAP;      // 512*3*SLOTCAP
    int*   bsums  = (int*)(wsF + (size_t)NBLK * 3 * SLOTCAP);
    float* minvec = (float*)(bsums + NBLK);

    count_k<<<CBLK, 512, 0, stream>>>(coord, minvec, wsD, wsI, wsF, bsums);
    write_k<<<NBLK, 256, 0, stream>>>(wsD, wsI, wsF, bsums, outF);
}

// Round 19
// 28.904 us; speedup vs baseline: 1.5677x; 1.5677x over previous
//
#include <hip/hip_runtime.h>
#include <float.h>

#define MM 256
#define PP 2097152            // fixed pair-list length
#define NBLK 512              // 512 slots: 128 structures x 4 row-blocks
#define CBLK 256              // count grid: 128 structures x 2 half-blocks
#define GTH (NBLK * 256)
#define CAP 2048              // staged pairs per flush batch
// Largest fp32 sq with rn(sqrt(sq)) < 5.0f  (== 25 - 2*ulp(25); boundary-exact)
#define SQMAX 24.999996185302734375f

typedef unsigned long long u64;

// ws layout: masks u64[GTH] | bsums int[NBLK] | minvec float[3]

__device__ inline void wave_min3(float& x, float& y, float& z) {
    #pragma unroll
    for (int off = 32; off > 0; off >>= 1) {
        x = fminf(x, __shfl_xor(x, off, 64));
        y = fminf(y, __shfl_xor(y, off, 64));
        z = fminf(z, __shfl_xor(z, off, 64));
    }
}

__device__ inline void zero_range(float* __restrict__ o, int lo, int hi, int g) {
    int a = (lo + 3) & ~3;           // hi is always a multiple of 4
    if (a > hi) a = hi;
    if (g < a - lo) o[lo + g] = 0.0f;
    float4* o4 = reinterpret_cast<float4*>(o);
    const float4 z4 = make_float4(0.f, 0.f, 0.f, 0.f);
    for (int q = (a >> 2) + g; q < (hi >> 2); q += GTH) o4[q] = z4;
}

// Bulk float4 flush of an LDS plane to global (pad-aligned; scalar edges).
__device__ inline void flush_plane(const float* __restrict__ lds, int n, int pad,
                                   float* __restrict__ gdst, int t) {
    if (n <= 0) return;
    const int end = pad + n;
    const int nb = (end + 3) >> 2;
    for (int m = t; m < nb; m += 256) {
        const int lo = m << 2;
        if (lo >= pad && lo + 4 <= end) {
            *reinterpret_cast<float4*>(gdst + lo) =
                *reinterpret_cast<const float4*>(lds + lo);
        } else {
            const int a = lo < pad ? pad : lo;
            const int bmax = (lo + 4 < end) ? (lo + 4) : end;
            for (int e = a; e < bmax; ++e) gdst[e] = lds[e];
        }
    }
}

// ---------------------------------------------------------------------------
// Geometry: slot b2 = b*4+rblk covers rows rblk*64..+64 of structure b;
// slot-thread tt = i_loc*4+c handles (row i_loc, j-chunk c); global slot
// b2*256+tt is lexicographic in (b,i,j). fp32 replicates the reference
// exactly: pos=coord-min (rn sub), diff=pos_j-pos_i, sq=((dx*dx+dy*dy)+dz*dz)
// no-FMA; membership sq<=SQMAX (== rn(sqrt(sq))<5 exactly); d=rn(sqrt) for
// hits only. fmin exact & order-independent -> matches jnp.min bitwise.
// ---------------------------------------------------------------------------

// K1 (256 blocks x 512 thr): redundant per-block GLOBAL coord min — now with
// STRIDE-1 float4 loads (1 KB/wave/instr) + %3 component demux (was stride-48
// triplets: 3x the L2 transactions — the round-18 decomposition showed this
// was the single biggest cost). Then count: bitmask -> masks, totals -> bsums.
__global__ void __launch_bounds__(512)
count_k(const float* __restrict__ coord, float* __restrict__ minvec,
        u64* __restrict__ masks, int* __restrict__ bsums) {
    const int cb = blockIdx.x;           // structure b = cb>>1, half = cb&1
    const int b = cb >> 1, h = cb & 1;
    const int t = threadIdx.x;           // 0..511
    const int lane = t & 63, w = t >> 6; // w 0..7

    __shared__ float4 tile4[4][65];
    __shared__ float lmin[3][8];
    __shared__ int wsum[8];

    // redundant global min over 24576 float4s, perfectly coalesced.
    // float4 j holds elems 4j..4j+3; comp(f.x)=comp(f.w)=j%3,
    // comp(f.y)=(j+1)%3, comp(f.z)=(j+2)%3.
    const float4* c4 = reinterpret_cast<const float4*>(coord);
    float mx = FLT_MAX, my = FLT_MAX, mz = FLT_MAX;
    int r = t % 3;                        // j%3 for j = 0*512 + t
    #pragma unroll 6
    for (int k = 0; k < 48; ++k) {
        const float4 f = c4[k * 512 + t];
        const float p = fminf(f.x, f.w);
        const float vx = (r == 0) ? p : ((r == 1) ? f.z : f.y);
        const float vy = (r == 1) ? p : ((r == 0) ? f.y : f.z);
        const float vz = (r == 2) ? p : ((r == 0) ? f.z : f.y);
        mx = fminf(mx, vx);
        my = fminf(my, vy);
        mz = fminf(mz, vz);
        r += 2; if (r >= 3) r -= 3;       // (j+512)%3 : 512 ≡ 2 (mod 3)
    }
    wave_min3(mx, my, mz);
    if (lane == 0) { lmin[0][w] = mx; lmin[1][w] = my; lmin[2][w] = mz; }
    __syncthreads();
    mx = fminf(fminf(fminf(lmin[0][0], lmin[0][1]), fminf(lmin[0][2], lmin[0][3])),
               fminf(fminf(lmin[0][4], lmin[0][5]), fminf(lmin[0][6], lmin[0][7])));
    my = fminf(fminf(fminf(lmin[1][0], lmin[1][1]), fminf(lmin[1][2], lmin[1][3])),
               fminf(fminf(lmin[1][4], lmin[1][5]), fminf(lmin[1][6], lmin[1][7])));
    mz = fminf(fminf(fminf(lmin[2][0], lmin[2][1]), fminf(lmin[2][2], lmin[2][3])),
               fminf(fminf(lmin[2][4], lmin[2][5]), fminf(lmin[2][6], lmin[2][7])));
    if (cb == 0 && t == 0) { minvec[0] = mx; minvec[1] = my; minvec[2] = mz; }

    // stage the whole structure's tile (shifted); threads 0..255
    if (t < 256) {
        const int ja = b * MM + t;
        tile4[t >> 6][t & 63] = make_float4(__fsub_rn(coord[3 * ja + 0], mx),
                                            __fsub_rn(coord[3 * ja + 1], my),
                                            __fsub_rn(coord[3 * ja + 2], mz), 0.0f);
    }
    __syncthreads();

    // count: hit bitmask (slot = cb*512 + t, lexicographic)
    const int rblk = 2 * h + (t >> 8);
    const int tt = t & 255;
    const int i_loc = tt >> 2, c = tt & 3;
    const float4 pi4 = tile4[rblk][i_loc];
    u64 m = 0ULL;
    for (int jj = 0; jj < 64; ++jj) {
        float4 v = tile4[c][jj];
        float dx = __fsub_rn(v.x, pi4.x);
        float dy = __fsub_rn(v.y, pi4.y);
        float dz = __fsub_rn(v.z, pi4.z);
        float sq = __fadd_rn(__fadd_rn(__fmul_rn(dx, dx), __fmul_rn(dy, dy)),
                             __fmul_rn(dz, dz));
        if (sq > 0.0f && sq <= SQMAX) m |= (1ULL << jj);
    }
    masks[cb * 512 + t] = m;

    int v = __popcll(m);
    #pragma unroll
    for (int off = 32; off > 0; off >>= 1) v += __shfl_xor(v, off, 64);
    if (lane == 0) wsum[w] = v;
    __syncthreads();
    if (t == 0) {
        bsums[cb * 2 + 0] = wsum[0] + wsum[1] + wsum[2] + wsum[3];
        bsums[cb * 2 + 1] = wsum[4] + wsum[5] + wsum[6] + wsum[7];
    }
}

// K2 (512 blocks x 256 thr): wave-0 register scan of 512 bsums -> base/total;
// staged emission with pad-aligned LDS planes -> float4 bulk flush; float4
// tail-zero. Output (floats): ind2 [0,2P) as {gi,gj}, d [2P,3P), df [3P,6P).
__global__ void __launch_bounds__(256)
write_k(const float* __restrict__ coord, const float* __restrict__ minvec,
        const u64* __restrict__ masks, const int* __restrict__ bsums,
        float* __restrict__ outF) {
    const int b2 = blockIdx.x;
    const int b = b2 >> 2, rblk = b2 & 3;
    const int t = threadIdx.x;
    const int lane = t & 63, w = t >> 6;

    __shared__ float4 tile4[4][65];
    __shared__ int pre[NBLK];
    __shared__ int sTot;
    __shared__ int wsum[4];
    __shared__ __align__(16) float sd[CAP + 4];        // dist plane
    __shared__ __align__(16) float sind[2 * CAP + 4];  // {gi,gj} plane
    __shared__ __align__(16) float sdf[3 * CAP + 4];   // {dx,dy,dz} plane

    const u64 mask = masks[b2 * 256 + t];              // issue early
    const float mnx = minvec[0], mny = minvec[1], mnz = minvec[2];
    const int ja = b * MM + t;
    tile4[w][lane] = make_float4(__fsub_rn(coord[3 * ja + 0], mnx),
                                 __fsub_rn(coord[3 * ja + 1], mny),
                                 __fsub_rn(coord[3 * ja + 2], mnz), 0.0f);

    // wave-0 register scan of the 512 block sums (single barrier)
    if (w == 0) {
        int v[8]; int s = 0;
        #pragma unroll
        for (int q = 0; q < 8; ++q) { v[q] = bsums[lane * 8 + q]; s += v[q]; }
        int isum = s;
        #pragma unroll
        for (int off = 1; off < 64; off <<= 1) {
            int u = __shfl_up(isum, off, 64);
            if (lane >= off) isum += u;
        }
        int run = isum - s;                       // exclusive prefix, lane-major
        #pragma unroll
        for (int q = 0; q < 8; ++q) { pre[lane * 8 + q] = run; run += v[q]; }
        if (lane == 63) sTot = run;               // grand total
    }
    __syncthreads();
    const int base = pre[b2];
    const int total = (sTot < PP) ? sTot : PP;

    // per-thread mask -> block-local exclusive offset + block total
    const int cnt = __popcll(mask);
    int incl = cnt;
    #pragma unroll
    for (int off = 1; off < 64; off <<= 1) {
        int v = __shfl_up(incl, off, 64);
        if (lane >= off) incl += v;
    }
    if (lane == 63) wsum[w] = incl;
    __syncthreads();
    const int agg = wsum[0] + wsum[1] + wsum[2] + wsum[3];
    int woff = 0;
    for (int k = 0; k < w; ++k) woff += wsum[k];
    const int lexcl = woff + incl - cnt;

    const int i_loc = t >> 2, c = t & 3;
    const float4 pi4 = tile4[rblk][i_loc];
    const int gi = b * MM + rblk * 64 + i_loc;
    const int gj0 = b * MM + c * 64;

    // staged emission; LDS planes pad-aligned so the flush is float4-bulk
    const int nbat = (agg + CAP - 1) / CAP;
    for (int bb = 0; bb < nbat; ++bb) {
        const int wlo = bb * CAP, whi = wlo + CAP;
        const int pbase = base + wlo;             // global pair idx of slot 0
        const int pd = pbase & 3;
        const int pi = (2 * pbase) & 3;
        const int pf = (3 * pbase) & 3;
        int q = lexcl;
        u64 mm = mask;
        while (mm) {
            const int jj = __ffsll((long long)mm) - 1;
            mm &= mm - 1;
            if (q >= whi) break;
            if (q >= wlo) {
                float4 v = tile4[c][jj];
                float dx = __fsub_rn(v.x, pi4.x);
                float dy = __fsub_rn(v.y, pi4.y);
                float dz = __fsub_rn(v.z, pi4.z);
                float sq = __fadd_rn(__fadd_rn(__fmul_rn(dx, dx), __fmul_rn(dy, dy)),
                                     __fmul_rn(dz, dz));
                const int s = q - wlo;
                sd[s + pd] = __fsqrt_rn(sq);
                sind[2 * s + pi + 0] = (float)gi;
                sind[2 * s + pi + 1] = (float)(gj0 + jj);
                sdf[3 * s + pf + 0] = dx;
                sdf[3 * s + pf + 1] = dy;
                sdf[3 * s + pf + 2] = dz;
            }
            q++;
        }
        __syncthreads();
        const int nq = ((agg - wlo) < CAP) ? (agg - wlo) : CAP;
        int rem = PP - pbase; if (rem < 0) rem = 0;
        const int nv = (nq < rem) ? nq : rem;     // clamp at PP
        flush_plane(sd,   nv,     pd, outF + 2 * PP + pbase - pd,     t);
        flush_plane(sind, 2 * nv, pi, outF + 2 * pbase - pi,          t);
        flush_plane(sdf,  3 * nv, pf, outF + 3 * PP + 3 * pbase - pf, t);
        __syncthreads();
    }

    // tail zeroing (disjoint from pair region; coalesced float4)
    const int g = b2 * 256 + t;
    zero_range(outF, 2 * total,          2 * PP, g);
    zero_range(outF, 2 * PP + total,     3 * PP, g);
    zero_range(outF, 3 * PP + 3 * total, 6 * PP, g);
}

extern "C" void kernel_launch(void* const* d_in, const int* in_sizes, int n_in,
                              void* d_out, int out_size, void* d_ws, size_t ws_size,
                              hipStream_t stream) {
    const float* coord = (const float*)d_in[0];
    // d_in[1] (ind_1) structurally encoded (B contiguous blocks of M); unused.
    float* outF = (float*)d_out;

    u64*   masks  = (u64*)d_ws;                    // GTH u64 = 1 MB
    int*   bsums  = (int*)(masks + GTH);           // 512 ints
    float* minvec = (float*)(bsums + NBLK);        // 3 floats

    count_k<<<CBLK, 512, 0, stream>>>(coord, minvec, masks, bsums);
    write_k<<<NBLK, 256, 0, stream>>>(coord, minvec, masks, bsums, outF);
}